// Round 11
// baseline (765.761 us; speedup 1.0000x reference)
//
#include <hip/hip_runtime.h>
#include <hip/hip_cooperative_groups.h>
#include <math.h>

namespace cg = cooperative_groups;

// Problem constants (B=8 batches, N=M=2048 points, D=3)
#define BATCH 8
#define NPTS 2048
#define THREADS 256            // 4 waves: 2 row-groups x 2 col-splits
#define HALF_COLS 1024         // columns staged per LDS stage
#define TILES_H 32             // 32-col MFMA tiles per staged half
#define ROWS_PER_BLOCK 64      // 2 row-groups of 32
#define NLOGICAL 1024          // 4 types x 8 batches x 32 row-blocks
#define LOG_M 7.62559580411076 // log(2048)

typedef __attribute__((ext_vector_type(8)))  __bf16 bf16x8;
typedef __attribute__((ext_vector_type(16))) float  f32x16;

union FragU { unsigned short u[8]; uint4 v; };

__device__ __forceinline__ unsigned short f2bf(float f) {
    union { float f; unsigned u; } x; x.f = f;
    unsigned r = x.u + 0x7FFFu + ((x.u >> 16) & 1u);   // RNE
    return (unsigned short)(r >> 16);
}
__device__ __forceinline__ float bf2f(unsigned short b) {
    union { unsigned u; float f; } x; x.u = ((unsigned)b) << 16;
    return x.f;
}

// Fused debiased-Sinkhorn: all 10 softmin rounds + output reduction in ONE
// cooperative kernel (grid.sync between rounds replaces 12 dependent
// launches; round 0 synthesizes zero potentials so no memset either).
// Inner round = r9's verified structure: single-pass softmin via 32x32x16
// MFMA, log2-domain args, estimated LSE shift (no max pass):
//   arg_ij = (x'_i . y'_j + pot_j - 0.5|y'_j|^2) * log2(e)/eps
// K=16 slots: (xh,xh,xl,xl)x(yh,yl,yh,yl) per dim (12), 3-way split of
// sigma*hhe vs 1.0 (3), slot 15 zero; sigma=log2e/eps. Shift
// m2_hat=(rowconst-old)/k2 enters as the MFMA C operand; res =
// old - k2*log2(s) (rowconst cancels); shift is ~44 log2 units off the true
// max worst-case, inside f32's ~116-unit slack.
// Persistent blocks: logical tiles 0..1023 strided by gridDim.x, so any
// co-resident grid size is correct; host sizes grid from the occupancy API.
// NO launch_bounds min-arg (r7: it caused 161 MB/dispatch scratch spill).
// Hybrid poly-exp2 reverted (r10: trans shares the VALU issue port; poly
// path at ~14 cyc/pair is strictly worse than native 8+2).
// A/B layout: m(n)=lane&31, k=(lane>>5)*8+j.
// C/D layout (verified m74/m101): col=lane&31, row=(reg&3)+8*(reg>>2)+4*(lane>>5).
__global__ __launch_bounds__(THREADS) void sinkhorn_fused(
    const float* __restrict__ x, const float* __restrict__ y,
    float* __restrict__ P0, float* __restrict__ P1, float* __restrict__ out)
{
    cg::grid_group gg = cg::this_grid();

    __shared__ uint4 BF[TILES_H][64];     // 32 KB: B frags (one half)
    __shared__ uint4 AF[2][64];           //  2 KB: A frags (2 row-groups)
    __shared__ float NM[ROWS_PER_BLOCK];  // -m2_hat per row
    __shared__ float SRED[2][2][32];      // partial sums [group][colsplit][row]

    const int lane  = threadIdx.x & 63;
    const int wave  = threadIdx.x >> 6;
    const int g     = wave >> 1;          // row-group 0..1
    const int c     = wave & 1;           // col-split 0..1
    const int khalf = lane >> 5;

    // Round schedule: r0 init (eps=diam^2, direct), r1..8 damped loop over
    // the eps ladder, r9 final extrapolation (direct write).
    const float epsR[10] = {4.0f, 4.0f, 4.0f, 1.0f, 0.25f, 0.0625f,
                            0.015625f, 0.00390625f, 0.0025f, 0.0025f};

    for (int r = 0; r < 10; ++r) {
        const float eps    = epsR[r];
        const float sigma  = (float)M_LOG2E / eps;
        const float k2     = eps * (float)M_LN2;
        const float inv_k2 = 1.0f / k2;
        const float rowc0  = eps * (float)LOG_M;
        const int   avg    = (r >= 1 && r <= 8);
        float*       dst = (r & 1) ? P1 : P0;
        const float* src = (r & 1) ? P0 : P1;   // r0: guarded, never read

        for (int lb = blockIdx.x; lb < NLOGICAL; lb += gridDim.x) {
            const int xblk  = lb & 31;
            const int batch = (lb >> 5) & 7;
            const int type  = lb >> 8;

            const float* rowP;
            const float* colP;
            int hslot, oslot;
            if (type == 0)      { rowP = x; colP = y; hslot = 1; oslot = 0; }  // f_ba
            else if (type == 1) { rowP = y; colP = x; hslot = 0; oslot = 1; }  // g_ab
            else if (type == 2) { rowP = x; colP = x; hslot = 2; oslot = 2; }  // f_aa
            else                { rowP = y; colP = y; hslot = 3; oslot = 3; }  // g_bb

            rowP += batch * NPTS * 3;
            colP += batch * NPTS * 3;
            const float* hP   = src + (hslot * BATCH + batch) * NPTS;
            const float* oldP = src + (oslot * BATCH + batch) * NPTS;
            float*       outP = dst + (oslot * BATCH + batch) * NPTS;

            __syncthreads();   // previous logical tile fully done with LDS

            // ---- stage A fragments (threads 0..127) ----
            if (threadIdx.x < 128) {
                const int ag = threadIdx.x >> 6, idx = threadIdx.x & 63;
                const int row = xblk * ROWS_PER_BLOCK + ag * 32 + (idx & 31);
                float x0 = rowP[3 * row + 0], x1 = rowP[3 * row + 1], x2 = rowP[3 * row + 2];
                float p0 = sigma * (x0 - 0.5f), p1 = sigma * (x1 - 0.5f), p2 = sigma * (x2 - 0.5f);
                unsigned short h0 = f2bf(p0); unsigned short l0 = f2bf(p0 - bf2f(h0));
                unsigned short h1 = f2bf(p1); unsigned short l1 = f2bf(p1 - bf2f(h1));
                unsigned short h2 = f2bf(p2); unsigned short l2 = f2bf(p2 - bf2f(h2));
                FragU f;
                if (idx < 32) {   // k0-7: dim0 (xh,xh,xl,xl), dim1 (xh,xh,xl,xl)
                    f.u[0] = h0; f.u[1] = h0; f.u[2] = l0; f.u[3] = l0;
                    f.u[4] = h1; f.u[5] = h1; f.u[6] = l1; f.u[7] = l1;
                } else {          // k8-15: dim2 (xh,xh,xl,xl), 1,1,1, 0
                    f.u[0] = h2; f.u[1] = h2; f.u[2] = l2; f.u[3] = l2;
                    f.u[4] = 0x3F80; f.u[5] = 0x3F80; f.u[6] = 0x3F80; f.u[7] = 0;
                }
                AF[ag][idx] = f.v;
            } else if (threadIdx.x < 128 + ROWS_PER_BLOCK) {
                // ---- per-row shift: NM[row] = (old - rowconst)/k2 ----
                const int rr = threadIdx.x - 128;
                const int i = xblk * ROWS_PER_BLOCK + rr;
                float x0 = rowP[3 * i + 0], x1 = rowP[3 * i + 1], x2 = rowP[3 * i + 2];
                float p0 = x0 - 0.5f, p1 = x1 - 0.5f, p2 = x2 - 0.5f;
                float rowconst = 0.5f * (p0 * p0 + p1 * p1 + p2 * p2) + rowc0;
                float oldv = r ? oldP[i] : 0.0f;
                NM[rr] = (oldv - rowconst) * inv_k2;
            }

            float s[16];
            #pragma unroll
            for (int q = 0; q < 16; ++q) s[q] = 0.0f;
            bf16x8 af;
            f32x16 nmv;

            // ---- two column halves, BF restaged between them ----
            for (int h = 0; h < 2; ++h) {
                if (h) __syncthreads();   // all waves done reading half 0

                for (int jj = threadIdx.x; jj < HALF_COLS; jj += THREADS) {
                    const int j = h * HALF_COLS + jj;
                    float y0 = colP[3 * j + 0], y1 = colP[3 * j + 1], y2 = colP[3 * j + 2];
                    float p0 = y0 - 0.5f, p1 = y1 - 0.5f, p2 = y2 - 0.5f;
                    unsigned short h0 = f2bf(p0); unsigned short l0 = f2bf(p0 - bf2f(h0));
                    unsigned short h1 = f2bf(p1); unsigned short l1 = f2bf(p1 - bf2f(h1));
                    unsigned short h2 = f2bf(p2); unsigned short l2 = f2bf(p2 - bf2f(h2));
                    float pot = r ? hP[j] : 0.0f;
                    float hhe = sigma * (pot - 0.5f * (p0 * p0 + p1 * p1 + p2 * p2));
                    unsigned short hA = f2bf(hhe); float r1 = hhe - bf2f(hA);
                    unsigned short hB = f2bf(r1);  float r2 = r1 - bf2f(hB);
                    unsigned short hC = f2bf(r2);
                    FragU f0, f1;
                    // k0-7: dim0 (yh,yl,yh,yl), dim1 (yh,yl,yh,yl)
                    f0.u[0] = h0; f0.u[1] = l0; f0.u[2] = h0; f0.u[3] = l0;
                    f0.u[4] = h1; f0.u[5] = l1; f0.u[6] = h1; f0.u[7] = l1;
                    // k8-15: dim2 (yh,yl,yh,yl), hA,hB,hC, 0
                    f1.u[0] = h2; f1.u[1] = l2; f1.u[2] = h2; f1.u[3] = l2;
                    f1.u[4] = hA; f1.u[5] = hB; f1.u[6] = hC; f1.u[7] = 0;
                    BF[jj >> 5][jj & 31]        = f0.v;   // k0-7  (lanes 0-31)
                    BF[jj >> 5][32 + (jj & 31)] = f1.v;   // k8-15 (lanes 32-63)
                }
                __syncthreads();

                if (h == 0) {   // A-frags / NM ready after first barrier
                    af = *(const bf16x8*)&AF[g][lane];
                    #pragma unroll
                    for (int q = 0; q < 16; ++q) {
                        const int row = (q & 3) + 8 * (q >> 2) + 4 * khalf;
                        nmv[q] = NM[g * 32 + row];
                    }
                }

                // this wave's 16 tiles of the staged 32
                const int tbase = c * (TILES_H / 2);
                #pragma unroll 2
                for (int t = 0; t < TILES_H / 2; ++t) {
                    bf16x8 bf = *(const bf16x8*)&BF[tbase + t][lane];
                    f32x16 acc = __builtin_amdgcn_mfma_f32_32x32x16_bf16(af, bf, nmv, 0, 0, 0);
                    #pragma unroll
                    for (int q = 0; q < 16; ++q)
                        s[q] += __builtin_amdgcn_exp2f(acc[q]);
                }
            }

            // ---- reduce over the 32 cols held across lanes ----
            #pragma unroll
            for (int off = 1; off <= 16; off <<= 1)
                #pragma unroll
                for (int q = 0; q < 16; ++q)
                    s[q] += __shfl_xor(s[q], off, 64);

            // ---- write col-split partials; merge; epilogue ----
            if ((lane & 31) == 0) {
                #pragma unroll
                for (int q = 0; q < 16; ++q) {
                    const int row = (q & 3) + 8 * (q >> 2) + 4 * khalf;
                    SRED[g][c][row] = s[q];
                }
            }
            __syncthreads();

            if (threadIdx.x < ROWS_PER_BLOCK) {
                const int p = threadIdx.x >> 5, rr = threadIdx.x & 31;
                const int i = xblk * ROWS_PER_BLOCK + p * 32 + rr;
                float sum = SRED[p][0][rr] + SRED[p][1][rr];
                float oldv = r ? oldP[i] : 0.0f;
                float res = oldv - k2 * __log2f(sum);
                outP[i] = avg ? 0.5f * (oldv + res) : res;
            }
        }
        gg.sync();   // all potentials of round r visible device-wide
    }

    // ---- out[b] = mean_i (f_ba - f_aa) + mean_j (g_ab - g_bb); pot in P1 ----
    for (int b = blockIdx.x; b < BATCH; b += gridDim.x) {
        const float* fba = P1 + (0 * BATCH + b) * NPTS;
        const float* gab = P1 + (1 * BATCH + b) * NPTS;
        const float* faa = P1 + (2 * BATCH + b) * NPTS;
        const float* gbb = P1 + (3 * BATCH + b) * NPTS;

        float s = 0.0f;
        for (int i = threadIdx.x; i < NPTS; i += THREADS)
            s += (fba[i] - faa[i]) + (gab[i] - gbb[i]);

        #pragma unroll
        for (int off = 32; off >= 1; off >>= 1)
            s += __shfl_xor(s, off, 64);

        __syncthreads();
        if (lane == 0) NM[wave] = s;   // reuse NM as the block-reduce buffer
        __syncthreads();
        if (threadIdx.x == 0) {
            float t = NM[0] + NM[1] + NM[2] + NM[3];
            out[b] = t * (1.0f / NPTS);
        }
    }
}

extern "C" void kernel_launch(void* const* d_in, const int* in_sizes, int n_in,
                              void* d_out, int out_size, void* d_ws, size_t ws_size,
                              hipStream_t stream)
{
    const float* x = (const float*)d_in[0];
    const float* y = (const float*)d_in[1];
    float* out = (float*)d_out;

    const size_t potElems = (size_t)4 * BATCH * NPTS;
    float* P0 = (float*)d_ws;
    float* P1 = P0 + potElems;

    // Persistent cooperative grid: size to guaranteed co-residency.
    int maxB = 0;
    if (hipOccupancyMaxActiveBlocksPerMultiprocessor(
            &maxB, (const void*)sinkhorn_fused, THREADS, 0) != hipSuccess || maxB < 1)
        maxB = 1;                     // 1 block/CU always fits (35 KB LDS)
    int nblocks = maxB * 256;         // 256 CUs on MI355X
    if (nblocks > NLOGICAL) nblocks = NLOGICAL;

    void* args[] = {(void*)&x, (void*)&y, (void*)&P0, (void*)&P1, (void*)&out};
    hipLaunchCooperativeKernel((const void*)sinkhorn_fused,
                               dim3(nblocks), dim3(THREADS), args, 0, stream);
}

// Round 12
// 474.928 us; speedup vs baseline: 1.6124x; 1.6124x over previous
//
#include <hip/hip_runtime.h>
#include <math.h>

// Problem constants (B=8 batches, N=M=2048 points, D=3)
#define BATCH 8
#define NPTS 2048
#define THREADS 256            // 4 waves: 2 row-groups x 2 col-splits
#define HALF_COLS 1024         // columns staged per LDS stage
#define TILES_H 32             // 32-col MFMA tiles per staged half
#define ROWS_PER_BLOCK 64      // 2 row-groups of 32
#define NLOGICAL 1024          // 4 types x 8 batches x 32 row-blocks
#define NCNT 64                // barrier arrival counters (64B-strided)
#define LOG_M 7.62559580411076 // log(2048)

typedef __attribute__((ext_vector_type(8)))  __bf16 bf16x8;
typedef __attribute__((ext_vector_type(16))) float  f32x16;

union FragU { unsigned short u[8]; uint4 v; };

__device__ __forceinline__ unsigned short f2bf(float f) {
    union { float f; unsigned u; } x; x.f = f;
    unsigned r = x.u + 0x7FFFu + ((x.u >> 16) & 1u);   // RNE
    return (unsigned short)(r >> 16);
}
__device__ __forceinline__ float bf2f(unsigned short b) {
    union { unsigned u; float f; } x; x.u = ((unsigned)b) << 16;
    return x.f;
}

// Hierarchical grid barrier (replaces cg::grid sync, whose single-counter
// arrival serializes 1024 RMWs on one line ~ 100 us/sync — r11's killer).
// bar[0..1023]: 64 counters strided 16 uints (64 B). bar[1024]: flag (own
// line). Generation counting (counters only ever increment; target =
// gen * blocksPerCnt) -> no reset races. Producers release via
// __threadfence() (wbL2: potentials reach L3, the XCD-coherence point)
// BEFORE arrival; consumers observe flag then __threadfence() acquire
// (invalidate) before reading. Cooperative launch guarantees co-residency.
__device__ __forceinline__ void gridBarrier(unsigned* bar, unsigned gen) {
    const unsigned perCnt = gridDim.x >> 6;   // gridDim.x is a multiple of 64
    __syncthreads();
    if (threadIdx.x == 0) {
        __threadfence();   // release: write back this block's potentials
        __hip_atomic_fetch_add(&bar[(blockIdx.x & (NCNT - 1)) << 4], 1u,
                               __ATOMIC_RELAXED, __HIP_MEMORY_SCOPE_AGENT);
    }
    if (blockIdx.x == 0) {
        if (threadIdx.x < NCNT) {
            const unsigned tgt = gen * perCnt;
            while (__hip_atomic_load(&bar[threadIdx.x << 4],
                     __ATOMIC_RELAXED, __HIP_MEMORY_SCOPE_AGENT) < tgt)
                __builtin_amdgcn_s_sleep(1);
        }
        __syncthreads();
        if (threadIdx.x == 0)
            __hip_atomic_store(&bar[1024], gen,
                               __ATOMIC_RELAXED, __HIP_MEMORY_SCOPE_AGENT);
    }
    if (threadIdx.x == 0) {
        while (__hip_atomic_load(&bar[1024],
                 __ATOMIC_RELAXED, __HIP_MEMORY_SCOPE_AGENT) < gen)
            __builtin_amdgcn_s_sleep(1);
        __threadfence();   // acquire: invalidate stale L1/L2 lines
    }
    __syncthreads();
}

// Fused debiased-Sinkhorn: 10 softmin rounds + output reduction in ONE
// cooperative kernel. Inner round = r9's verified structure: single-pass
// softmin via 32x32x16 MFMA, log2-domain args, estimated LSE shift:
//   arg_ij = (x'_i . y'_j + pot_j - 0.5|y'_j|^2) * log2(e)/eps
// K=16 slots: (xh,xh,xl,xl)x(yh,yl,yh,yl) per dim (12), 3-way split of
// sigma*hhe vs 1.0 (3), slot 15 zero; sigma=log2e/eps. Shift
// m2_hat=(rowconst-old)/k2 enters as the MFMA C operand; res =
// old - k2*log2(s); shift is ~44 log2 units off worst-case (f32 slack ~116).
// NO launch_bounds min-arg (r7: caused 161 MB/dispatch scratch spill).
// A/B layout: m(n)=lane&31, k=(lane>>5)*8+j.
// C/D layout (verified m74/m101): col=lane&31, row=(reg&3)+8*(reg>>2)+4*(lane>>5).
__global__ __launch_bounds__(THREADS) void sinkhorn_fused(
    const float* __restrict__ x, const float* __restrict__ y,
    float* __restrict__ P0, float* __restrict__ P1,
    unsigned* __restrict__ bar, float* __restrict__ out)
{
    __shared__ uint4 BF[TILES_H][64];     // 32 KB: B frags (one half)
    __shared__ uint4 AF[2][64];           //  2 KB: A frags (2 row-groups)
    __shared__ float NM[ROWS_PER_BLOCK];  // -m2_hat per row
    __shared__ float SRED[2][2][32];      // partial sums [group][colsplit][row]

    const int lane  = threadIdx.x & 63;
    const int wave  = threadIdx.x >> 6;
    const int g     = wave >> 1;          // row-group 0..1
    const int c     = wave & 1;           // col-split 0..1
    const int khalf = lane >> 5;

    const float epsR[10] = {4.0f, 4.0f, 4.0f, 1.0f, 0.25f, 0.0625f,
                            0.015625f, 0.00390625f, 0.0025f, 0.0025f};

    for (int r = 0; r < 10; ++r) {
        const float eps    = epsR[r];
        const float sigma  = (float)M_LOG2E / eps;
        const float k2     = eps * (float)M_LN2;
        const float inv_k2 = 1.0f / k2;
        const float rowc0  = eps * (float)LOG_M;
        const int   avg    = (r >= 1 && r <= 8);
        float*       dst = (r & 1) ? P1 : P0;
        const float* src = (r & 1) ? P0 : P1;   // r0: guarded, never read

        for (int lb = blockIdx.x; lb < NLOGICAL; lb += gridDim.x) {
            const int xblk  = lb & 31;
            const int batch = (lb >> 5) & 7;
            const int type  = lb >> 8;

            const float* rowP;
            const float* colP;
            int hslot, oslot;
            if (type == 0)      { rowP = x; colP = y; hslot = 1; oslot = 0; }  // f_ba
            else if (type == 1) { rowP = y; colP = x; hslot = 0; oslot = 1; }  // g_ab
            else if (type == 2) { rowP = x; colP = x; hslot = 2; oslot = 2; }  // f_aa
            else                { rowP = y; colP = y; hslot = 3; oslot = 3; }  // g_bb

            rowP += batch * NPTS * 3;
            colP += batch * NPTS * 3;
            const float* hP   = src + (hslot * BATCH + batch) * NPTS;
            const float* oldP = src + (oslot * BATCH + batch) * NPTS;
            float*       outP = dst + (oslot * BATCH + batch) * NPTS;

            __syncthreads();   // previous logical tile fully done with LDS

            // ---- stage A fragments (threads 0..127) ----
            if (threadIdx.x < 128) {
                const int ag = threadIdx.x >> 6, idx = threadIdx.x & 63;
                const int row = xblk * ROWS_PER_BLOCK + ag * 32 + (idx & 31);
                float x0 = rowP[3 * row + 0], x1 = rowP[3 * row + 1], x2 = rowP[3 * row + 2];
                float p0 = sigma * (x0 - 0.5f), p1 = sigma * (x1 - 0.5f), p2 = sigma * (x2 - 0.5f);
                unsigned short h0 = f2bf(p0); unsigned short l0 = f2bf(p0 - bf2f(h0));
                unsigned short h1 = f2bf(p1); unsigned short l1 = f2bf(p1 - bf2f(h1));
                unsigned short h2 = f2bf(p2); unsigned short l2 = f2bf(p2 - bf2f(h2));
                FragU f;
                if (idx < 32) {   // k0-7: dim0 (xh,xh,xl,xl), dim1 (xh,xh,xl,xl)
                    f.u[0] = h0; f.u[1] = h0; f.u[2] = l0; f.u[3] = l0;
                    f.u[4] = h1; f.u[5] = h1; f.u[6] = l1; f.u[7] = l1;
                } else {          // k8-15: dim2 (xh,xh,xl,xl), 1,1,1, 0
                    f.u[0] = h2; f.u[1] = h2; f.u[2] = l2; f.u[3] = l2;
                    f.u[4] = 0x3F80; f.u[5] = 0x3F80; f.u[6] = 0x3F80; f.u[7] = 0;
                }
                AF[ag][idx] = f.v;
            } else if (threadIdx.x < 128 + ROWS_PER_BLOCK) {
                // ---- per-row shift: NM[row] = (old - rowconst)/k2 ----
                const int rr = threadIdx.x - 128;
                const int i = xblk * ROWS_PER_BLOCK + rr;
                float x0 = rowP[3 * i + 0], x1 = rowP[3 * i + 1], x2 = rowP[3 * i + 2];
                float p0 = x0 - 0.5f, p1 = x1 - 0.5f, p2 = x2 - 0.5f;
                float rowconst = 0.5f * (p0 * p0 + p1 * p1 + p2 * p2) + rowc0;
                float oldv = r ? oldP[i] : 0.0f;
                NM[rr] = (oldv - rowconst) * inv_k2;
            }

            float s[16];
            #pragma unroll
            for (int q = 0; q < 16; ++q) s[q] = 0.0f;
            bf16x8 af;
            f32x16 nmv;

            // ---- two column halves, BF restaged between them ----
            for (int h = 0; h < 2; ++h) {
                if (h) __syncthreads();   // all waves done reading half 0

                for (int jj = threadIdx.x; jj < HALF_COLS; jj += THREADS) {
                    const int j = h * HALF_COLS + jj;
                    float y0 = colP[3 * j + 0], y1 = colP[3 * j + 1], y2 = colP[3 * j + 2];
                    float p0 = y0 - 0.5f, p1 = y1 - 0.5f, p2 = y2 - 0.5f;
                    unsigned short h0 = f2bf(p0); unsigned short l0 = f2bf(p0 - bf2f(h0));
                    unsigned short h1 = f2bf(p1); unsigned short l1 = f2bf(p1 - bf2f(h1));
                    unsigned short h2 = f2bf(p2); unsigned short l2 = f2bf(p2 - bf2f(h2));
                    float pot = r ? hP[j] : 0.0f;
                    float hhe = sigma * (pot - 0.5f * (p0 * p0 + p1 * p1 + p2 * p2));
                    unsigned short hA = f2bf(hhe); float r1 = hhe - bf2f(hA);
                    unsigned short hB = f2bf(r1);  float r2 = r1 - bf2f(hB);
                    unsigned short hC = f2bf(r2);
                    FragU f0, f1;
                    // k0-7: dim0 (yh,yl,yh,yl), dim1 (yh,yl,yh,yl)
                    f0.u[0] = h0; f0.u[1] = l0; f0.u[2] = h0; f0.u[3] = l0;
                    f0.u[4] = h1; f0.u[5] = l1; f0.u[6] = h1; f0.u[7] = l1;
                    // k8-15: dim2 (yh,yl,yh,yl), hA,hB,hC, 0
                    f1.u[0] = h2; f1.u[1] = l2; f1.u[2] = h2; f1.u[3] = l2;
                    f1.u[4] = hA; f1.u[5] = hB; f1.u[6] = hC; f1.u[7] = 0;
                    BF[jj >> 5][jj & 31]        = f0.v;   // k0-7  (lanes 0-31)
                    BF[jj >> 5][32 + (jj & 31)] = f1.v;   // k8-15 (lanes 32-63)
                }
                __syncthreads();

                if (h == 0) {   // A-frags / NM ready after first barrier
                    af = *(const bf16x8*)&AF[g][lane];
                    #pragma unroll
                    for (int q = 0; q < 16; ++q) {
                        const int row = (q & 3) + 8 * (q >> 2) + 4 * khalf;
                        nmv[q] = NM[g * 32 + row];
                    }
                }

                // this wave's 16 tiles of the staged 32
                const int tbase = c * (TILES_H / 2);
                #pragma unroll 2
                for (int t = 0; t < TILES_H / 2; ++t) {
                    bf16x8 bf = *(const bf16x8*)&BF[tbase + t][lane];
                    f32x16 acc = __builtin_amdgcn_mfma_f32_32x32x16_bf16(af, bf, nmv, 0, 0, 0);
                    #pragma unroll
                    for (int q = 0; q < 16; ++q)
                        s[q] += __builtin_amdgcn_exp2f(acc[q]);
                }
            }

            // ---- reduce over the 32 cols held across lanes ----
            #pragma unroll
            for (int off = 1; off <= 16; off <<= 1)
                #pragma unroll
                for (int q = 0; q < 16; ++q)
                    s[q] += __shfl_xor(s[q], off, 64);

            // ---- write col-split partials; merge; epilogue ----
            if ((lane & 31) == 0) {
                #pragma unroll
                for (int q = 0; q < 16; ++q) {
                    const int row = (q & 3) + 8 * (q >> 2) + 4 * khalf;
                    SRED[g][c][row] = s[q];
                }
            }
            __syncthreads();

            if (threadIdx.x < ROWS_PER_BLOCK) {
                const int p = threadIdx.x >> 5, rr = threadIdx.x & 31;
                const int i = xblk * ROWS_PER_BLOCK + p * 32 + rr;
                float sum = SRED[p][0][rr] + SRED[p][1][rr];
                float oldv = r ? oldP[i] : 0.0f;
                float res = oldv - k2 * __log2f(sum);
                outP[i] = avg ? 0.5f * (oldv + res) : res;
            }
        }
        gridBarrier(bar, (unsigned)(r + 1));   // potentials of round r visible
    }

    // ---- out[b] = mean_i (f_ba - f_aa) + mean_j (g_ab - g_bb); pot in P1 ----
    for (int b = blockIdx.x; b < BATCH; b += gridDim.x) {
        const float* fba = P1 + (0 * BATCH + b) * NPTS;
        const float* gab = P1 + (1 * BATCH + b) * NPTS;
        const float* faa = P1 + (2 * BATCH + b) * NPTS;
        const float* gbb = P1 + (3 * BATCH + b) * NPTS;

        float s = 0.0f;
        for (int i = threadIdx.x; i < NPTS; i += THREADS)
            s += (fba[i] - faa[i]) + (gab[i] - gbb[i]);

        #pragma unroll
        for (int off = 32; off >= 1; off >>= 1)
            s += __shfl_xor(s, off, 64);

        __syncthreads();
        if (lane == 0) NM[wave] = s;   // reuse NM as the block-reduce buffer
        __syncthreads();
        if (threadIdx.x == 0) {
            float t = NM[0] + NM[1] + NM[2] + NM[3];
            out[b] = t * (1.0f / NPTS);
        }
    }
}

extern "C" void kernel_launch(void* const* d_in, const int* in_sizes, int n_in,
                              void* d_out, int out_size, void* d_ws, size_t ws_size,
                              hipStream_t stream)
{
    const float* x = (const float*)d_in[0];
    const float* y = (const float*)d_in[1];
    float* out = (float*)d_out;

    const size_t potElems = (size_t)4 * BATCH * NPTS;
    float* P0 = (float*)d_ws;
    float* P1 = P0 + potElems;
    unsigned* bar = (unsigned*)(P1 + potElems);   // 64 counters + flag

    // Zero barrier state every launch (ws is re-poisoned before each call).
    hipMemsetAsync(bar, 0, (1024 + 16) * sizeof(unsigned), stream);

    // Persistent cooperative grid sized for guaranteed co-residency.
    int maxB = 0;
    if (hipOccupancyMaxActiveBlocksPerMultiprocessor(
            &maxB, (const void*)sinkhorn_fused, THREADS, 0) != hipSuccess || maxB < 1)
        maxB = 1;                     // 1 block/CU always fits (35 KB LDS)
    int nblocks = maxB * 256;         // multiple of 64 by construction
    if (nblocks > NLOGICAL) nblocks = NLOGICAL;

    void* args[] = {(void*)&x, (void*)&y, (void*)&P0, (void*)&P1,
                    (void*)&bar, (void*)&out};
    hipLaunchCooperativeKernel((const void*)sinkhorn_fused,
                               dim3(nblocks), dim3(THREADS), args, 0, stream);
}

// Round 13
// 381.937 us; speedup vs baseline: 2.0049x; 1.2435x over previous
//
#include <hip/hip_runtime.h>
#include <math.h>

// Problem constants (B=8 batches, N=M=2048 points, D=3)
#define BATCH 8
#define NPTS 2048
#define THREADS 256            // 4 waves: 2 row-groups x 2 col-splits
#define HALF_COLS 1024         // columns staged per LDS stage
#define TILES_H 32             // 32-col MFMA tiles per staged half
#define ROWS_PER_BLOCK 64      // 2 row-groups of 32
#define LOG_M 7.62559580411076 // log(2048)

typedef __attribute__((ext_vector_type(8)))  __bf16 bf16x8;
typedef __attribute__((ext_vector_type(16))) float  f32x16;

union FragU { unsigned short u[8]; uint4 v; };

__device__ __forceinline__ unsigned short f2bf(float f) {
    union { float f; unsigned u; } x; x.f = f;
    unsigned r = x.u + 0x7FFFu + ((x.u >> 16) & 1u);   // RNE
    return (unsigned short)(r >> 16);
}
__device__ __forceinline__ float bf2f(unsigned short b) {
    union { unsigned u; float f; } x; x.u = ((unsigned)b) << 16;
    return x.f;
}

// Softmin via 32x32x16 MFMA, log2-domain args, estimated LSE shift:
//   arg_ij = (x'_i . y'_j + pot_j - 0.5|y'_j|^2) * log2(e)/eps
// Shift m2hat = (rowconst - old)/k2 as the MFMA C operand; res =
// old - k2*log2(sum 2^arg) (rowconst cancels).
//
// Round 13 — TRANSPOSE IDENTITY: with this shift, the shifted matrix for
// the xy pass is EXACTLY symmetric between the f_ba and g_ab softmins
// (hx_i - nmx_i = log2(M) = -(nmy_j - hy_j), factors cancel). So ONE pass
// over the xy matrix yields f_ba (row sums) AND g_ab (column sums) — the
// type-1 matrix pass (25% of all exp2/MFMA work) is deleted. Column
// partials (this block's 64 rows) go to per-block slices csDst[xblk][j]
// (no atomics/zeroing; ping-pong); consumers reconstruct g_ab lazily next
// round: g_ab = gbase[j] - pk2*log2(sum_blk cs[blk][j]), where gbase/pk2
// are the producing round's old value / effective k2. Launch boundary is
// the producer->consumer sync (multi-launch; r11/12 showed software grid
// barriers cost ~28 us/round vs ~3 us launch gaps).
// grid.z: 0 = xy (f_ba + g_ab), 1 = xx (f_aa), 2 = yy (g_bb).
// NO launch_bounds min-arg (r7: caused 161 MB/dispatch scratch spill).
// A/B layout: m(n)=lane&31, k=(lane>>5)*8+j.
// C/D layout (verified m74/m101): col=lane&31, row=(reg&3)+8*(reg>>2)+4*(lane>>5).
__global__ __launch_bounds__(THREADS) void softmin_pass(
    const float* __restrict__ x, const float* __restrict__ y,
    const float* __restrict__ potSrc, float* __restrict__ potDst,
    const float* __restrict__ csSrc, float* __restrict__ csDst,
    float sigma, float k2, float inv_k2, float rowc0, float pk2,
    int avg, int first)
{
    __shared__ uint4 BF[TILES_H][64];     // 32 KB: B frags (one half)
    __shared__ uint4 AF[2][64];           //  2 KB: A frags (2 row-groups)
    __shared__ float NM[ROWS_PER_BLOCK];  // -m2hat per row
    __shared__ float SRED[2][2][32];      // rowsum partials [grp][csplit][row]
    float* colLDS = (float*)&BF[0][0];    // 8 KB alias, used after BF reads

    const int xblk  = blockIdx.x;
    const int batch = blockIdx.y;
    const int type  = blockIdx.z;
    const int isXY  = (type == 0);

    const float* rowP;
    const float* colP;
    int hslot, oslot;
    if (type == 0)      { rowP = x; colP = y; hslot = 1; oslot = 0; }  // f_ba (+g_ab via cols)
    else if (type == 1) { rowP = x; colP = x; hslot = 2; oslot = 2; }  // f_aa
    else                { rowP = y; colP = y; hslot = 3; oslot = 3; }  // g_bb

    rowP += batch * NPTS * 3;
    colP += batch * NPTS * 3;
    const float* hP   = potSrc + (hslot * BATCH + batch) * NPTS;  // types 1,2
    const float* oldP = potSrc + (oslot * BATCH + batch) * NPTS;
    float*       outP = potDst + (oslot * BATCH + batch) * NPTS;
    const float* gbS  = potSrc + (1 * BATCH + batch) * NPTS;      // g_ab base (lazy)
    float*       gbD  = potDst + (1 * BATCH + batch) * NPTS;
    const float* csS  = csSrc + (size_t)batch * 32 * NPTS;
    float*       csD  = csDst + (size_t)batch * 32 * NPTS + (size_t)xblk * NPTS;

    // ---- stage A fragments (threads 0..127) ----
    if (threadIdx.x < 128) {
        const int ag = threadIdx.x >> 6, idx = threadIdx.x & 63;
        const int row = xblk * ROWS_PER_BLOCK + ag * 32 + (idx & 31);
        float x0 = rowP[3 * row + 0], x1 = rowP[3 * row + 1], x2 = rowP[3 * row + 2];
        float p0 = sigma * (x0 - 0.5f), p1 = sigma * (x1 - 0.5f), p2 = sigma * (x2 - 0.5f);
        unsigned short h0 = f2bf(p0); unsigned short l0 = f2bf(p0 - bf2f(h0));
        unsigned short h1 = f2bf(p1); unsigned short l1 = f2bf(p1 - bf2f(h1));
        unsigned short h2 = f2bf(p2); unsigned short l2 = f2bf(p2 - bf2f(h2));
        FragU f;
        if (idx < 32) {   // k0-7: dim0 (xh,xh,xl,xl), dim1 (xh,xh,xl,xl)
            f.u[0] = h0; f.u[1] = h0; f.u[2] = l0; f.u[3] = l0;
            f.u[4] = h1; f.u[5] = h1; f.u[6] = l1; f.u[7] = l1;
        } else {          // k8-15: dim2 (xh,xh,xl,xl), 1,1,1, 0
            f.u[0] = h2; f.u[1] = h2; f.u[2] = l2; f.u[3] = l2;
            f.u[4] = 0x3F80; f.u[5] = 0x3F80; f.u[6] = 0x3F80; f.u[7] = 0;
        }
        AF[ag][idx] = f.v;
    } else if (threadIdx.x < 128 + ROWS_PER_BLOCK) {
        // ---- per-row shift: NM[row] = (old - rowconst)/k2 ----
        const int rr = threadIdx.x - 128;
        const int i = xblk * ROWS_PER_BLOCK + rr;
        float x0 = rowP[3 * i + 0], x1 = rowP[3 * i + 1], x2 = rowP[3 * i + 2];
        float p0 = x0 - 0.5f, p1 = x1 - 0.5f, p2 = x2 - 0.5f;
        float rowconst = 0.5f * (p0 * p0 + p1 * p1 + p2 * p2) + rowc0;
        float oldv = first ? 0.0f : oldP[i];
        NM[rr] = (oldv - rowconst) * inv_k2;
    }

    const int lane  = threadIdx.x & 63;
    const int wave  = threadIdx.x >> 6;
    const int g     = wave >> 1;          // row-group 0..1
    const int c     = wave & 1;           // col-split 0..1
    const int khalf = lane >> 5;

    float s[16];
    #pragma unroll
    for (int q = 0; q < 16; ++q) s[q] = 0.0f;
    float colv[32];                       // per-lane column partials (xy only)
    #pragma unroll
    for (int q = 0; q < 32; ++q) colv[q] = 0.0f;
    bf16x8 af;
    f32x16 nmv;

    // ---- two column halves, BF restaged between them ----
    for (int h = 0; h < 2; ++h) {
        if (h) __syncthreads();   // all waves done reading half 0

        for (int jj = threadIdx.x; jj < HALF_COLS; jj += THREADS) {
            const int j = h * HALF_COLS + jj;
            float y0 = colP[3 * j + 0], y1 = colP[3 * j + 1], y2 = colP[3 * j + 2];
            float p0 = y0 - 0.5f, p1 = y1 - 0.5f, p2 = y2 - 0.5f;
            unsigned short h0 = f2bf(p0); unsigned short l0 = f2bf(p0 - bf2f(h0));
            unsigned short h1 = f2bf(p1); unsigned short l1 = f2bf(p1 - bf2f(h1));
            unsigned short h2 = f2bf(p2); unsigned short l2 = f2bf(p2 - bf2f(h2));
            float pot;
            if (isXY) {
                if (first) pot = 0.0f;
                else {   // lazy g_ab finalize: base + slice-sum from prev round
                    float cs = 0.0f;
                    #pragma unroll 8
                    for (int b2 = 0; b2 < 32; ++b2) cs += csS[b2 * NPTS + j];
                    pot = gbS[j] - pk2 * __log2f(cs);
                }
                if ((j >> 6) == xblk) gbD[j] = pot;   // own chunk: materialize
            } else {
                pot = first ? 0.0f : hP[j];
            }
            float hhe = sigma * (pot - 0.5f * (p0 * p0 + p1 * p1 + p2 * p2));
            unsigned short hA = f2bf(hhe); float r1 = hhe - bf2f(hA);
            unsigned short hB = f2bf(r1);  float r2 = r1 - bf2f(hB);
            unsigned short hC = f2bf(r2);
            FragU f0, f1;
            // k0-7: dim0 (yh,yl,yh,yl), dim1 (yh,yl,yh,yl)
            f0.u[0] = h0; f0.u[1] = l0; f0.u[2] = h0; f0.u[3] = l0;
            f0.u[4] = h1; f0.u[5] = l1; f0.u[6] = h1; f0.u[7] = l1;
            // k8-15: dim2 (yh,yl,yh,yl), hA,hB,hC, 0
            f1.u[0] = h2; f1.u[1] = l2; f1.u[2] = h2; f1.u[3] = l2;
            f1.u[4] = hA; f1.u[5] = hB; f1.u[6] = hC; f1.u[7] = 0;
            BF[jj >> 5][jj & 31]        = f0.v;   // k0-7  (lanes 0-31)
            BF[jj >> 5][32 + (jj & 31)] = f1.v;   // k8-15 (lanes 32-63)
        }
        __syncthreads();

        if (h == 0) {   // A-frags / NM ready after first barrier
            af = *(const bf16x8*)&AF[g][lane];
            #pragma unroll
            for (int q = 0; q < 16; ++q) {
                const int row = (q & 3) + 8 * (q >> 2) + 4 * khalf;
                nmv[q] = NM[g * 32 + row];
            }
        }

        // this wave's 16 tiles of the staged 32
        const int tbase = c * (TILES_H / 2);
        if (isXY) {
            #pragma unroll 2
            for (int t = 0; t < TILES_H / 2; ++t) {
                bf16x8 bf = *(const bf16x8*)&BF[tbase + t][lane];
                f32x16 acc = __builtin_amdgcn_mfma_f32_32x32x16_bf16(af, bf, nmv, 0, 0, 0);
                float cv = 0.0f;
                #pragma unroll
                for (int q = 0; q < 16; ++q) {
                    float e = __builtin_amdgcn_exp2f(acc[q]);
                    s[q] += e;            // row sums -> f_ba
                    cv   += e;            // column partial -> g_ab
                }
                colv[h * 16 + t] = cv;
            }
        } else {
            #pragma unroll 2
            for (int t = 0; t < TILES_H / 2; ++t) {
                bf16x8 bf = *(const bf16x8*)&BF[tbase + t][lane];
                f32x16 acc = __builtin_amdgcn_mfma_f32_32x32x16_bf16(af, bf, nmv, 0, 0, 0);
                #pragma unroll
                for (int q = 0; q < 16; ++q)
                    s[q] += __builtin_amdgcn_exp2f(acc[q]);
            }
        }
    }

    // ---- row sums across the 32 cols held by lanes ----
    #pragma unroll
    for (int off = 1; off <= 16; off <<= 1)
        #pragma unroll
        for (int q = 0; q < 16; ++q)
            s[q] += __shfl_xor(s[q], off, 64);
    if ((lane & 31) == 0) {
        #pragma unroll
        for (int q = 0; q < 16; ++q) {
            const int row = (q & 3) + 8 * (q >> 2) + 4 * khalf;
            SRED[g][c][row] = s[q];
        }
    }

    // ---- column partials: merge khalf pairs (same col, rows +-16) ----
    if (isXY) {
        #pragma unroll
        for (int q = 0; q < 32; ++q)
            colv[q] += __shfl_xor(colv[q], 32, 64);
    }
    __syncthreads();   // BF reads done (alias safe), SRED visible

    if (isXY) {
        // accumulate the two row-groups' partials in LDS, then store slice
        if (g == 0 && lane < 32) {
            #pragma unroll
            for (int q = 0; q < 32; ++q) {
                const int col = (q >> 4) * 1024 + (c * 16 + (q & 15)) * 32 + (lane & 31);
                colLDS[col] = colv[q];
            }
        }
        __syncthreads();
        if (g == 1 && lane < 32) {
            #pragma unroll
            for (int q = 0; q < 32; ++q) {
                const int col = (q >> 4) * 1024 + (c * 16 + (q & 15)) * 32 + (lane & 31);
                colLDS[col] += colv[q];
            }
        }
        __syncthreads();
        for (int j = threadIdx.x; j < NPTS; j += THREADS)
            csD[j] = colLDS[j];
    }

    // ---- epilogue: res = old - k2*log2(rowsum) for this block's 64 rows ----
    if (threadIdx.x < ROWS_PER_BLOCK) {
        const int p = threadIdx.x >> 5, rr = threadIdx.x & 31;
        const int i = xblk * ROWS_PER_BLOCK + p * 32 + rr;
        float sum = SRED[p][0][rr] + SRED[p][1][rr];
        float oldv = first ? 0.0f : oldP[i];
        float res = oldv - k2 * __log2f(sum);
        outP[i] = avg ? 0.5f * (oldv + res) : res;
    }
}

// out[b] = mean_i (f_ba - f_aa) + mean_j (g_ab - g_bb); g_ab lazily
// finalized from gbase + final-round column slices.
__global__ void reduce_out(const float* __restrict__ pot,
                           const float* __restrict__ csF, float pk2,
                           float* __restrict__ out)
{
    const int b = blockIdx.x;
    const float* fba = pot + (0 * BATCH + b) * NPTS;
    const float* gb  = pot + (1 * BATCH + b) * NPTS;
    const float* faa = pot + (2 * BATCH + b) * NPTS;
    const float* gbb = pot + (3 * BATCH + b) * NPTS;
    const float* csB = csF + (size_t)b * 32 * NPTS;

    float s = 0.0f;
    for (int i = threadIdx.x; i < NPTS; i += THREADS) {
        float cs = 0.0f;
        #pragma unroll 8
        for (int b2 = 0; b2 < 32; ++b2) cs += csB[b2 * NPTS + i];
        float gab = gb[i] - pk2 * __log2f(cs);
        s += (fba[i] - faa[i]) + (gab - gbb[i]);
    }

    #pragma unroll
    for (int off = 32; off >= 1; off >>= 1)
        s += __shfl_xor(s, off, 64);

    __shared__ float red[THREADS / 64];
    const int lane = threadIdx.x & 63;
    const int wave = threadIdx.x >> 6;
    if (lane == 0) red[wave] = s;
    __syncthreads();
    if (threadIdx.x == 0) {
        float t = 0.0f;
        for (int w = 0; w < THREADS / 64; ++w) t += red[w];
        out[b] = t * (1.0f / NPTS);
    }
}

extern "C" void kernel_launch(void* const* d_in, const int* in_sizes, int n_in,
                              void* d_out, int out_size, void* d_ws, size_t ws_size,
                              hipStream_t stream)
{
    const float* x = (const float*)d_in[0];
    const float* y = (const float*)d_in[1];
    float* out = (float*)d_out;

    // ws layout: P0, P1 (4 slots x B x NPTS each), CS0, CS1 (B x 32 x NPTS).
    const size_t potElems = (size_t)4 * BATCH * NPTS;
    const size_t csElems  = (size_t)BATCH * 32 * NPTS;
    float* P0  = (float*)d_ws;
    float* P1  = P0 + potElems;
    float* CS0 = P1 + potElems;
    float* CS1 = CS0 + csElems;
    // No memset needed: round 0 (first=1) never reads src/cs buffers.

    // 10 rounds: init(4), damped over [4,4,1,0.25,...,0.0025], final(0.0025)
    const double epsR[10] = {4.0, 4.0, 4.0, 1.0, 0.25, 0.0625,
                             0.015625, 0.00390625, 0.0025, 0.0025};
    const int    avgR[10] = {0, 1, 1, 1, 1, 1, 1, 1, 1, 0};

    dim3 grid(NPTS / ROWS_PER_BLOCK, BATCH, 3);
    float pk2 = 0.0f;   // effective k2 of the producing (previous) round
    for (int r = 0; r < 10; ++r) {
        const double eps = epsR[r];
        float sigma  = (float)(M_LOG2E / eps);
        float k2     = (float)(eps * M_LN2);
        float inv_k2 = (float)(1.0 / (eps * M_LN2));
        float rowc0  = (float)(eps * LOG_M);
        float* dst = (r & 1) ? P1 : P0;
        float* src = (r & 1) ? P0 : P1;
        float* csD = (r & 1) ? CS1 : CS0;
        float* csS = (r & 1) ? CS0 : CS1;
        softmin_pass<<<grid, THREADS, 0, stream>>>(
            x, y, src, dst, csS, csD,
            sigma, k2, inv_k2, rowc0, pk2, avgR[r], r == 0);
        pk2 = (avgR[r] ? 0.5f : 1.0f) * k2;
    }

    // Final potentials in P1 (round 9 dst), final slices in CS1.
    reduce_out<<<dim3(BATCH), THREADS, 0, stream>>>(P1, CS1, pk2, out);
}

// Round 14
// 266.568 us; speedup vs baseline: 2.8727x; 1.4328x over previous
//
#include <hip/hip_runtime.h>
#include <math.h>

// Problem constants (B=8 batches, N=M=2048 points, D=3)
#define BATCH 8
#define NPTS 2048
#define THREADS 256            // 4 waves: 2 row-groups x 2 col-splits
#define HALF_COLS 1024         // columns staged per LDS stage
#define TILES_H 32             // 32-col MFMA tiles per staged half
#define ROWS_PER_BLOCK 64      // 2 row-groups of 32
#define LOG_M 7.62559580411076 // log(2048)

typedef __attribute__((ext_vector_type(8)))  __bf16 bf16x8;
typedef __attribute__((ext_vector_type(16))) float  f32x16;

union FragU { unsigned short u[8]; uint4 v; };

__device__ __forceinline__ unsigned short f2bf(float f) {
    union { float f; unsigned u; } x; x.f = f;
    unsigned r = x.u + 0x7FFFu + ((x.u >> 16) & 1u);   // RNE
    return (unsigned short)(r >> 16);
}
__device__ __forceinline__ float bf2f(unsigned short b) {
    union { unsigned u; float f; } x; x.u = ((unsigned)b) << 16;
    return x.f;
}

// Single-pass softmin via 32x32x16 MFMA with estimated LSE shift (no max pass).
//   arg_ij = (x'_i . y'_j + pot_j - 0.5|y'_j|^2) * log2(e)/eps  (log2 domain)
// K=16 slots: per dim, (xh,xh,xl,xl)x(yh,yl,yh,yl) = 4 products (12 slots),
// 3-way split of sigma*hhe vs 1.0 (3 slots), slot 15 zero; sigma=log2e/eps.
// Shift m2_hat = (rowconst - old)/k2 enters as the MFMA C operand;
// res = old - k2*log2(s) (rowconst cancels); shift is ~44 log2 units off
// worst-case, inside f32's ~116-unit slack.
// This is the r9 structure (best verified: 268 us total), reverted from the
// r10/r11/r12/r13 experiments which all measured worse:
//  - r10 poly-exp2 on VALU: regressed (trans shares the wave issue port;
//    v_exp_f32 effectively ~13-16 issue-cyc, poly ~14 cyc/pair is no better)
//  - r11/r12 single-kernel fusion: grid-barrier + agent fences cost
//    ~28-100 us/round vs ~3 us launch gaps
//  - r13 transpose identity (-25% exp2): +32 VGPR colsum state and extra
//    barriers/finalize cost more than the arithmetic saved
// Round 14 delta vs r9: the final round (last=1) folds the output reduction
// in via one atomicAdd per block (sign by type), deleting reduce_out.
// NO launch_bounds min-arg (r7: it caused 161 MB/dispatch scratch spill).
// A/B layout: m(n)=lane&31, k=(lane>>5)*8+j.
// C/D layout (verified m74/m101): col=lane&31, row=(reg&3)+8*(reg>>2)+4*(lane>>5).
__global__ __launch_bounds__(THREADS) void softmin_pass(
    const float* __restrict__ x, const float* __restrict__ y,
    const float* __restrict__ potSrc, float* __restrict__ potDst,
    float sigma, float k2, float inv_k2, float rowc0, int avg, int last,
    float* __restrict__ out)
{
    __shared__ uint4 BF[TILES_H][64];     // 32 KB: B frags (one half), slot=lane
    __shared__ uint4 AF[2][64];           //  2 KB: A frags (2 row-groups)
    __shared__ float NM[ROWS_PER_BLOCK];  // -m2_hat per row
    __shared__ float SRED[2][2][32];      // partial sums [group][colsplit][row]

    const int type  = blockIdx.z;
    const int batch = blockIdx.y;

    const float* rowP;
    const float* colP;
    int hslot, oslot;
    if (type == 0)      { rowP = x; colP = y; hslot = 1; oslot = 0; }  // f_ba
    else if (type == 1) { rowP = y; colP = x; hslot = 0; oslot = 1; }  // g_ab
    else if (type == 2) { rowP = x; colP = x; hslot = 2; oslot = 2; }  // f_aa
    else                { rowP = y; colP = y; hslot = 3; oslot = 3; }  // g_bb

    rowP += batch * NPTS * 3;
    colP += batch * NPTS * 3;
    const float* hP   = potSrc + (hslot * BATCH + batch) * NPTS;
    const float* oldP = potSrc + (oslot * BATCH + batch) * NPTS;
    float*       outP = potDst + (oslot * BATCH + batch) * NPTS;

    // ---- stage A fragments: 2 groups x 64 slots = threads 0..127 ----
    if (threadIdx.x < 128) {
        const int g = threadIdx.x >> 6, idx = threadIdx.x & 63;
        const int row = blockIdx.x * ROWS_PER_BLOCK + g * 32 + (idx & 31);
        float x0 = rowP[3 * row + 0], x1 = rowP[3 * row + 1], x2 = rowP[3 * row + 2];
        float p0 = sigma * (x0 - 0.5f), p1 = sigma * (x1 - 0.5f), p2 = sigma * (x2 - 0.5f);
        unsigned short h0 = f2bf(p0); unsigned short l0 = f2bf(p0 - bf2f(h0));
        unsigned short h1 = f2bf(p1); unsigned short l1 = f2bf(p1 - bf2f(h1));
        unsigned short h2 = f2bf(p2); unsigned short l2 = f2bf(p2 - bf2f(h2));
        FragU f;
        if (idx < 32) {   // k0-7: dim0 (xh,xh,xl,xl), dim1 (xh,xh,xl,xl)
            f.u[0] = h0; f.u[1] = h0; f.u[2] = l0; f.u[3] = l0;
            f.u[4] = h1; f.u[5] = h1; f.u[6] = l1; f.u[7] = l1;
        } else {          // k8-15: dim2 (xh,xh,xl,xl), 1,1,1, 0
            f.u[0] = h2; f.u[1] = h2; f.u[2] = l2; f.u[3] = l2;
            f.u[4] = 0x3F80; f.u[5] = 0x3F80; f.u[6] = 0x3F80; f.u[7] = 0;
        }
        AF[g][idx] = f.v;
    } else if (threadIdx.x < 128 + ROWS_PER_BLOCK) {
        // ---- per-row shift: NM[r] = (old - rowconst)/k2 = -m2_hat ----
        const int r = threadIdx.x - 128;
        const int i = blockIdx.x * ROWS_PER_BLOCK + r;
        float x0 = rowP[3 * i + 0], x1 = rowP[3 * i + 1], x2 = rowP[3 * i + 2];
        float p0 = x0 - 0.5f, p1 = x1 - 0.5f, p2 = x2 - 0.5f;
        float rowconst = 0.5f * (p0 * p0 + p1 * p1 + p2 * p2) + rowc0;
        NM[r] = (oldP[i] - rowconst) * inv_k2;
    }

    const int lane = threadIdx.x & 63;
    const int wave = threadIdx.x >> 6;
    const int g    = wave >> 1;        // row-group 0..1
    const int c    = wave & 1;         // col-split 0..1
    const int khalf = lane >> 5;

    float s[16];
    #pragma unroll
    for (int r = 0; r < 16; ++r) s[r] = 0.0f;
    bf16x8 af;
    f32x16 nmv;

    // ---- two column halves, BF restaged between them ----
    for (int h = 0; h < 2; ++h) {
        if (h) __syncthreads();   // all waves done reading previous half

        // stage B fragments for this half (1024 cols, all 256 threads)
        for (int jj = threadIdx.x; jj < HALF_COLS; jj += THREADS) {
            const int j = h * HALF_COLS + jj;
            float y0 = colP[3 * j + 0], y1 = colP[3 * j + 1], y2 = colP[3 * j + 2];
            float p0 = y0 - 0.5f, p1 = y1 - 0.5f, p2 = y2 - 0.5f;
            unsigned short h0 = f2bf(p0); unsigned short l0 = f2bf(p0 - bf2f(h0));
            unsigned short h1 = f2bf(p1); unsigned short l1 = f2bf(p1 - bf2f(h1));
            unsigned short h2 = f2bf(p2); unsigned short l2 = f2bf(p2 - bf2f(h2));
            float hhe = sigma * (hP[j] - 0.5f * (p0 * p0 + p1 * p1 + p2 * p2));
            unsigned short hA = f2bf(hhe); float r1 = hhe - bf2f(hA);
            unsigned short hB = f2bf(r1);  float r2 = r1 - bf2f(hB);
            unsigned short hC = f2bf(r2);
            FragU f0, f1;
            // k0-7: dim0 (yh,yl,yh,yl), dim1 (yh,yl,yh,yl)
            f0.u[0] = h0; f0.u[1] = l0; f0.u[2] = h0; f0.u[3] = l0;
            f0.u[4] = h1; f0.u[5] = l1; f0.u[6] = h1; f0.u[7] = l1;
            // k8-15: dim2 (yh,yl,yh,yl), hA,hB,hC, 0
            f1.u[0] = h2; f1.u[1] = l2; f1.u[2] = h2; f1.u[3] = l2;
            f1.u[4] = hA; f1.u[5] = hB; f1.u[6] = hC; f1.u[7] = 0;
            BF[jj >> 5][jj & 31]        = f0.v;   // k0-7  (lanes 0-31)
            BF[jj >> 5][32 + (jj & 31)] = f1.v;   // k8-15 (lanes 32-63)
        }
        __syncthreads();

        if (h == 0) {   // A-frags / NM ready after first barrier
            af = *(const bf16x8*)&AF[g][lane];
            #pragma unroll
            for (int r = 0; r < 16; ++r) {
                const int row = (r & 3) + 8 * (r >> 2) + 4 * khalf;
                nmv[r] = NM[g * 32 + row];
            }
        }

        // this wave's 16 tiles of the staged 32
        const int tbase = c * (TILES_H / 2);
        #pragma unroll 2
        for (int t = 0; t < TILES_H / 2; ++t) {
            bf16x8 bf = *(const bf16x8*)&BF[tbase + t][lane];
            f32x16 acc = __builtin_amdgcn_mfma_f32_32x32x16_bf16(af, bf, nmv, 0, 0, 0);
            #pragma unroll
            for (int r = 0; r < 16; ++r)
                s[r] += __builtin_amdgcn_exp2f(acc[r]);
        }
    }

    // ---- reduce over the 32 cols held across lanes (xor 1..16) ----
    #pragma unroll
    for (int off = 1; off <= 16; off <<= 1)
        #pragma unroll
        for (int r = 0; r < 16; ++r)
            s[r] += __shfl_xor(s[r], off, 64);

    // ---- write col-split partials; merge; epilogue ----
    if ((lane & 31) == 0) {
        #pragma unroll
        for (int r = 0; r < 16; ++r) {
            const int row = (r & 3) + 8 * (r >> 2) + 4 * khalf;
            SRED[g][c][row] = s[r];
        }
    }
    __syncthreads();

    if (threadIdx.x < ROWS_PER_BLOCK) {
        const int p = threadIdx.x >> 5, r = threadIdx.x & 31;
        const int i = blockIdx.x * ROWS_PER_BLOCK + p * 32 + r;
        float sum = SRED[p][0][r] + SRED[p][1][r];
        float oldv = oldP[i];
        float res = oldv - k2 * __log2f(sum);
        outP[i] = avg ? 0.5f * (oldv + res) : res;
        if (last) NM[threadIdx.x] = res;   // stash for the output reduction
    }

    // ---- last round: out[b] += sign * sum(res)/N, one atomic per block ----
    if (last) {
        __syncthreads();
        if (wave == 0) {   // threads 0..63 re-reduce the 64 stashed values
            float v = NM[lane];
            #pragma unroll
            for (int off = 32; off >= 1; off >>= 1)
                v += __shfl_xor(v, off, 64);
            if (lane == 0) {
                float sign = (type >= 2) ? -1.0f : 1.0f;   // f_aa,g_bb subtract
                atomicAdd(out + batch, sign * v * (1.0f / NPTS));
            }
        }
    }
}

extern "C" void kernel_launch(void* const* d_in, const int* in_sizes, int n_in,
                              void* d_out, int out_size, void* d_ws, size_t ws_size,
                              hipStream_t stream)
{
    const float* x = (const float*)d_in[0];
    const float* y = (const float*)d_in[1];
    float* out = (float*)d_out;

    // Ping-pong potential buffers in workspace: [4 slots][B][NPTS] each.
    const size_t potElems = (size_t)4 * BATCH * NPTS;
    float* P0 = (float*)d_ws;
    float* P1 = P0 + potElems;

    // Zero the initial potentials (h = a_log exactly at init; old = 0)
    // and the 8 output accumulators (harness poisons d_out each replay).
    hipMemsetAsync(P0, 0, potElems * sizeof(float), stream);
    hipMemsetAsync(out, 0, BATCH * sizeof(float), stream);

    // Epsilon schedule: [diam^p] + exp(arange(p ln diam, p ln blur, p ln scale)) + [blur^p]
    double epsl[16];
    int ne = 0;
    epsl[ne++] = 4.0;                       // diameter^2
    const double stop = 2.0 * log(0.05);
    const double step = 2.0 * log(0.5);
    for (double e = 2.0 * log(2.0); e > stop; e += step)
        epsl[ne++] = exp(e);                // 4, 1, 0.25, 0.0625, 0.015625, 0.00390625
    epsl[ne++] = 0.05 * 0.05;               // blur^2 = 0.0025

    float* src = P0;
    float* dst = P1;
    dim3 grid(NPTS / ROWS_PER_BLOCK, BATCH, 4);

    auto launch = [&](double eps, int avg, int last) {
        float sigma  = (float)(M_LOG2E / eps);   // K=16, no k-dup
        float k2     = (float)(eps * M_LN2);
        float inv_k2 = (float)(1.0 / (eps * M_LN2));
        float rowc0  = (float)(eps * LOG_M);
        softmin_pass<<<grid, THREADS, 0, stream>>>(
            x, y, src, dst, sigma, k2, inv_k2, rowc0, avg, last, out);
        float* t = src; src = dst; dst = t;
    };

    launch(epsl[0], 0, 0);                    // init (writes direct)
    for (int k = 0; k < ne; ++k)
        launch(epsl[k], 1, 0);                // damped symmetric Sinkhorn
    launch(epsl[ne - 1], 0, 1);               // final extrapolation + output
}